// Round 10
// baseline (17.537 us; speedup 1.0000x reference)
//
#include <hip/hip_runtime.h>
#include <math.h>

// field[c,x,y] = sum_n exp(-(x-xc[n])^2/(2s^2)) * exp(-(y-yc[n])^2/(2s^2)) * v[c,n]
// v = init_vectors * (32/(W+L)), s = 32. Output [1,2,W,L] fp32, y fastest.
//
// R9: instruction-contiguous stores. Tile 16x(y=256); wave w owns rows
// 4w..4w+3, lane owns y=lane*4 -> every global_store_dwordx4 covers 1 KB
// contiguous in one row (previous rounds: <=128B chunks at 8KB stride per
// instruction — never actually tested until now). ey[256] per bump filled
// cooperatively (batch 4 bumps, 2 barriers/batch); ex[16] per bump.
// Scan/stage kept from R3. R_CUT=112 (3.5 sigma).

#define N_MAX  512
#define TX     16
#define TY     256
#define R_CUT  112.0f
#define BATCH  4

#define EXP2F(x) __builtin_amdgcn_exp2f(x)

typedef float f4 __attribute__((ext_vector_type(4)));

__global__ __launch_bounds__(256, 4) void motion_field_kernel(
    const float* __restrict__ init_vectors,  // [2, N]
    const int*   __restrict__ x_coord,       // [N]
    const int*   __restrict__ y_coord,       // [N]
    const int*   __restrict__ d_width,       // [1]
    const int*   __restrict__ d_lenth,       // [1]
    float*       __restrict__ out,           // [2, W, L]
    int N, int W, int L)
{
    __shared__ float2 s_xy[N_MAX];           // (xc*S, yc*S)
    __shared__ float2 s_v[N_MAX];            // (v0, v1) prescaled
    __shared__ short  s_list[N_MAX];
    __shared__ int    s_cnt[4];
    __shared__ float  s_ey[BATCH][TY];       // 4 KB
    __shared__ float  s_ex[BATCH][TX];       // 256 B

    const int tid  = threadIdx.x;
    const int wave = tid >> 6;               // 0..3 -> rows 4w..4w+3
    const int lane = tid & 63;               // y = lane*4

    // S = sqrt(log2(e)/(2*32*32)); exp(-d^2/2048) = exp2(-(d*S)^2)
    const float S = 0.02654008814f;
    const float scale = 32.0f / (float)(d_width[0] + d_lenth[0]);  // MAGNITUDE=1

    for (int i = tid; i < N; i += 256) {
        s_xy[i] = make_float2((float)x_coord[i] * S, (float)y_coord[i] * S);
        s_v[i]  = make_float2(init_vectors[i] * scale,
                              init_vectors[N + i] * scale);
    }
    __syncthreads();

    const int x0 = blockIdx.x * TX;
    const int y0 = blockIdx.y * TY;
    const float bx_lo = ((float)x0 - R_CUT) * S;
    const float bx_hi = ((float)(x0 + TX - 1) + R_CUT) * S;
    const float by_lo = ((float)y0 - R_CUT) * S;
    const float by_hi = ((float)(y0 + TY - 1) + R_CUT) * S;

    // ---- wave-parallel scan + deterministic ballot compaction ----
    int total = 0;
    for (int base_n = 0; base_n < N; base_n += 256) {
        const int n = base_n + tid;
        bool pred = false;
        if (n < N) {
            const float2 xy = s_xy[n];
            pred = (xy.x >= bx_lo) && (xy.x <= bx_hi) &&
                   (xy.y >= by_lo) && (xy.y <= by_hi);
        }
        const unsigned long long mk = __ballot(pred);
        if (lane == 0) s_cnt[wave] = __popcll(mk);
        __syncthreads();
        const int c0 = s_cnt[0], c1 = s_cnt[1], c2 = s_cnt[2], c3 = s_cnt[3];
        int base = total;
        if (wave > 0) base += c0;
        if (wave > 1) base += c1;
        if (wave > 2) base += c2;
        if (pred) {
            const int pos = base + __popcll(mk & ((1ULL << lane) - 1ULL));
            s_list[pos] = (short)n;
        }
        total += c0 + c1 + c2 + c3;
        __syncthreads();
    }
    const int M = total;

    // acc[c][row] over 4 y-px (lane's quad): 32 floats
    f4 acc[2][4];
    #pragma unroll
    for (int c = 0; c < 2; ++c)
        #pragma unroll
        for (int i = 0; i < 4; ++i) acc[c][i] = (f4){0.f, 0.f, 0.f, 0.f};

    const float Yl = (float)(y0 + lane * 4) * S;  // lane's y base (scaled)

    for (int m0 = 0; m0 < M; m0 += BATCH) {
        const int B = (M - m0 < BATCH) ? (M - m0) : BATCH;

        // ey fill: B*256 slots; thread s covers (b = s>>8, y = s&255)
        for (int s = tid; s < B * TY; s += 256) {
            const int b = s >> 8, y = s & (TY - 1);
            const int n = (int)s_list[m0 + b];
            const float dy = (float)(y0 + y) * S - s_xy[n].y;
            s_ey[b][y] = EXP2F(-(dy * dy));
        }
        // ex fill: B*16 slots (<=64), threads 0..63
        if (tid < B * TX) {
            const int b = tid >> 4, r = tid & (TX - 1);
            const int n = (int)s_list[m0 + b];
            const float dx = (float)(x0 + r) * S - s_xy[n].x;
            s_ex[b][r] = EXP2F(-(dx * dx));
        }
        __syncthreads();

        for (int b = 0; b < B; ++b) {
            const int n = (int)s_list[m0 + b];
            const float2 v = s_v[n];
            // wave's 4 rows: one broadcast f4; lane's 4 y: one b128 read
            const f4 ex4 = *(const f4*)&s_ex[b][wave * 4];
            const f4 ey4 = *(const f4*)&s_ey[b][lane * 4];
            const float exs[4] = {ex4.x, ex4.y, ex4.z, ex4.w};
            #pragma unroll
            for (int i = 0; i < 4; ++i) {
                acc[0][i] += ey4 * (exs[i] * v.x);
                acc[1][i] += ey4 * (exs[i] * v.y);
            }
        }
        __syncthreads();
    }

    // stores: per instr, 64 lanes x 16 B = 1 KB contiguous in one row
    const size_t WL = (size_t)W * (size_t)L;
    const int yb = y0 + lane * 4;
    #pragma unroll
    for (int c = 0; c < 2; ++c) {
        #pragma unroll
        for (int i = 0; i < 4; ++i) {
            const int x = x0 + wave * 4 + i;
            *(f4*)&out[(size_t)c * WL + (size_t)x * L + (size_t)yb] = acc[c][i];
        }
    }
}

extern "C" void kernel_launch(void* const* d_in, const int* in_sizes, int n_in,
                              void* d_out, int out_size, void* d_ws, size_t ws_size,
                              hipStream_t stream) {
    const float* init_vectors = (const float*)d_in[0];
    const int*   x_coord      = (const int*)d_in[1];
    const int*   y_coord      = (const int*)d_in[2];
    const int*   d_width      = (const int*)d_in[3];
    const int*   d_lenth      = (const int*)d_in[4];
    float*       out          = (float*)d_out;

    const int N = in_sizes[1];                 // 512
    const int WL = out_size / 2;
    int W = 1;
    while ((long long)W * (long long)W < (long long)WL) W <<= 1;
    const int L = WL / W;                      // 2048, 2048

    dim3 grid(W / TX, L / TY);                 // 128 x 8 = 1024 blocks
    dim3 block(256);
    hipLaunchKernelGGL(motion_field_kernel, grid, block, 0, stream,
                       init_vectors, x_coord, y_coord, d_width, d_lenth,
                       out, N, W, L);
}

// Round 11
// 15.216 us; speedup vs baseline: 1.1526x; 1.1526x over previous
//
#include <hip/hip_runtime.h>
#include <math.h>

// field[c,x,y] = sum_n exp(-(x-xc[n])^2/(2s^2)) * exp(-(y-yc[n])^2/(2s^2)) * v[c,n]
// v = init_vectors * (32/(W+L)), s = 32. Output [1,2,W,L] fp32, y fastest.
//
// R10: R3 (best known, 15.49us) VERBATIM with ONE isolated change: output
// stores -> __builtin_nontemporal_store (L2 no-allocate). Theory: output
// (33.5MB ~ aggregate L2) sits dirty in per-XCD L2 at kernel end and the
// end-of-dispatch writeback drain (~5us) serializes after compute; nt stores
// stream to HBM during the kernel instead. R5's nt test was confounded with
// a tile-shape change; this is the clean A/B.

#define N_MAX  512
#define TX     32
#define TY     64
#define R_CUT  128.0f
#define BATCH  8

#define EXP2F(x) __builtin_amdgcn_exp2f(x)

typedef float f4 __attribute__((ext_vector_type(4)));

__global__ __launch_bounds__(256, 8) void motion_field_kernel(
    const float* __restrict__ init_vectors,  // [2, N]
    const int*   __restrict__ x_coord,       // [N]
    const int*   __restrict__ y_coord,       // [N]
    const int*   __restrict__ d_width,       // [1]
    const int*   __restrict__ d_lenth,       // [1]
    float*       __restrict__ out,           // [2, W, L]
    int N, int W, int L)
{
    __shared__ float s_xc[N_MAX], s_yc[N_MAX], s_v0[N_MAX], s_v1[N_MAX];
    __shared__ short s_list[N_MAX];
    __shared__ int   s_cnt[4];
    __shared__ float s_ex[BATCH][TX];
    __shared__ float s_ey[BATCH][TY];

    const int tid  = threadIdx.x;
    const int wave = tid >> 6;
    const int lane = tid & 63;

    const float scale = 32.0f / (float)(d_width[0] + d_lenth[0]);  // MAGNITUDE=1

    for (int i = tid; i < N; i += 256) {
        s_xc[i] = (float)x_coord[i];
        s_yc[i] = (float)y_coord[i];
        s_v0[i] = init_vectors[i] * scale;
        s_v1[i] = init_vectors[N + i] * scale;
    }
    __syncthreads();

    const int x0 = blockIdx.x * TX;
    const int y0 = blockIdx.y * TY;
    const float bx_lo = (float)x0 - R_CUT;
    const float bx_hi = (float)(x0 + TX - 1) + R_CUT;
    const float by_lo = (float)y0 - R_CUT;
    const float by_hi = (float)(y0 + TY - 1) + R_CUT;

    // ---- wave-parallel scan + deterministic ballot compaction ----
    int total = 0;
    for (int base_n = 0; base_n < N; base_n += 256) {
        const int n = base_n + tid;
        bool pred = false;
        if (n < N) {
            const float xc = s_xc[n], yc = s_yc[n];
            pred = (xc >= bx_lo) && (xc <= bx_hi) && (yc >= by_lo) && (yc <= by_hi);
        }
        const unsigned long long m = __ballot(pred);
        if (lane == 0) s_cnt[wave] = __popcll(m);
        __syncthreads();
        const int c0 = s_cnt[0], c1 = s_cnt[1], c2 = s_cnt[2], c3 = s_cnt[3];
        int base = total;
        if (wave > 0) base += c0;
        if (wave > 1) base += c1;
        if (wave > 2) base += c2;
        if (pred) {
            const int pos = base + __popcll(m & ((1ULL << lane) - 1ULL));
            s_list[pos] = (short)n;
        }
        total += c0 + c1 + c2 + c3;
        __syncthreads();
    }
    const int M = total;

    // thread covers 2x x 4y pixels: u = x sub-block (0..15), v = y sub-block (0..15)
    const int u = tid >> 4;
    const int v = tid & 15;

    float acc0[2][4], acc1[2][4];
    #pragma unroll
    for (int i = 0; i < 2; ++i)
        #pragma unroll
        for (int j = 0; j < 4; ++j) { acc0[i][j] = 0.f; acc1[i][j] = 0.f; }

    // exp(-d^2/(2*32*32)) = exp2(d^2 * C2), C2 = -log2(e)/2048
    const float C2 = -1.4426950408889634f / 2048.0f;

    for (int m0 = 0; m0 < M; m0 += BATCH) {
        const int B = (M - m0 < BATCH) ? (M - m0) : BATCH;
        // ex fill: B*TX slots (<=256 -> single pass)
        for (int s = tid; s < B * TX; s += 256) {
            const int b = s >> 5, r = s & (TX - 1);
            const int n = (int)s_list[m0 + b];
            const float dx = (float)(x0 + r) - s_xc[n];
            s_ex[b][r] = EXP2F(dx * dx * C2);
        }
        // ey fill: B*TY slots (<=512 -> two passes)
        for (int s = tid; s < B * TY; s += 256) {
            const int b = s >> 6, r = s & (TY - 1);
            const int n = (int)s_list[m0 + b];
            const float dy = (float)(y0 + r) - s_yc[n];
            s_ey[b][r] = EXP2F(dy * dy * C2);
        }
        __syncthreads();

        for (int b = 0; b < B; ++b) {
            const int n = (int)s_list[m0 + b];
            const float v0 = s_v0[n], v1 = s_v1[n];
            const float2 ex2 = *reinterpret_cast<const float2*>(&s_ex[b][u * 2]);
            const float4 ey4 = *reinterpret_cast<const float4*>(&s_ey[b][v * 4]);
            const float exs[2] = {ex2.x, ex2.y};
            const float eys[4] = {ey4.x, ey4.y, ey4.z, ey4.w};
            #pragma unroll
            for (int i = 0; i < 2; ++i) {
                const float e0 = exs[i] * v0;
                const float e1 = exs[i] * v1;
                #pragma unroll
                for (int j = 0; j < 4; ++j) {
                    acc0[i][j] = fmaf(e0, eys[j], acc0[i][j]);
                    acc1[i][j] = fmaf(e1, eys[j], acc1[i][j]);
                }
            }
        }
        __syncthreads();
    }

    // out[c*W*L + x*L + y]; nontemporal f4 stores (L2 no-allocate) — the ONE
    // change vs R3.
    const size_t WL = (size_t)W * (size_t)L;
    const int xb = x0 + u * 2;
    const int yb = y0 + v * 4;
    #pragma unroll
    for (int i = 0; i < 2; ++i) {
        const size_t x = (size_t)(xb + i);
        f4 o0 = (f4){acc0[i][0], acc0[i][1], acc0[i][2], acc0[i][3]};
        f4 o1 = (f4){acc1[i][0], acc1[i][1], acc1[i][2], acc1[i][3]};
        __builtin_nontemporal_store(o0, (f4*)&out[x * (size_t)L + (size_t)yb]);
        __builtin_nontemporal_store(o1, (f4*)&out[WL + x * (size_t)L + (size_t)yb]);
    }
}

extern "C" void kernel_launch(void* const* d_in, const int* in_sizes, int n_in,
                              void* d_out, int out_size, void* d_ws, size_t ws_size,
                              hipStream_t stream) {
    const float* init_vectors = (const float*)d_in[0];
    const int*   x_coord      = (const int*)d_in[1];
    const int*   y_coord      = (const int*)d_in[2];
    const int*   d_width      = (const int*)d_in[3];
    const int*   d_lenth      = (const int*)d_in[4];
    float*       out          = (float*)d_out;

    const int N = in_sizes[1];                 // 512
    const int WL = out_size / 2;
    int W = 1;
    while ((long long)W * (long long)W < (long long)WL) W <<= 1;
    const int L = WL / W;                      // 2048, 2048

    dim3 grid(W / TX, L / TY);                 // 64 x 32 = 2048 blocks
    dim3 block(256);
    hipLaunchKernelGGL(motion_field_kernel, grid, block, 0, stream,
                       init_vectors, x_coord, y_coord, d_width, d_lenth,
                       out, N, W, L);
}